// Round 2
// baseline (164.106 us; speedup 1.0000x reference)
//
#include <hip/hip_runtime.h>

#define NN 1024
#define HH 128
#define QR 2
#define TPB 512

__device__ __forceinline__ float wmaxf(float v) {
#pragma unroll
  for (int off = 1; off < 64; off <<= 1) v = fmaxf(v, __shfl_xor(v, off));
  return v;
}
__device__ __forceinline__ float wsumf(float v) {
#pragma unroll
  for (int off = 1; off < 64; off <<= 1) v += __shfl_xor(v, off);
  return v;
}

// ---------------- prep: W transposes + edge param pack + c0 ----------------
__global__ __launch_bounds__(128)
void prep_kernel(const float* __restrict__ Wq, const float* __restrict__ Wk,
                 const float* __restrict__ Wv, const float* __restrict__ We1,
                 const float* __restrict__ be1, const float* __restrict__ We2,
                 const float* __restrict__ be2, const float* __restrict__ Wc,
                 const float* __restrict__ bc,
                 float* __restrict__ WqT, float* __restrict__ WkT,
                 float* __restrict__ WvT, float* __restrict__ epack,
                 float* __restrict__ c0) {
  const int d = blockIdx.x;
  const int o = threadIdx.x;
  WqT[d * HH + o] = Wq[o * HH + d];
  WkT[d * HH + o] = Wk[o * HH + d];
  WvT[d * HH + o] = Wv[o * HH + d];
  if (d == 0) {
    // u[t] = sum_e Wc[e] * We2[e][t]   (fold Wc @ We2)
    float uu = 0.f;
    for (int e = 0; e < HH; ++e) uu = fmaf(Wc[e], We2[e * HH + o], uu);
    epack[o * 4 + 0] = We1[2 * o];
    epack[o * 4 + 1] = We1[2 * o + 1];
    epack[o * 4 + 2] = be1[o];
    epack[o * 4 + 3] = uu;
    if (o == 0) {
      float s = bc[0];
      for (int e = 0; e < HH; ++e) s = fmaf(Wc[e], be2[e], s);
      c0[0] = s;
    }
  }
}

// ---------------- qkv projections: q (pre-scaled), v row-major; k transposed ----------------
__global__ __launch_bounds__(128)
void qkv_kernel(const float* __restrict__ hin,
                const float* __restrict__ WqT, const float* __restrict__ WkT,
                const float* __restrict__ WvT,
                const float* __restrict__ bq, const float* __restrict__ bk,
                const float* __restrict__ bv,
                float* __restrict__ q, float* __restrict__ kT,
                float* __restrict__ v) {
  __shared__ __align__(16) float hT[HH][QR];
  const int tid = threadIdx.x;   // output feature o
  const int i0 = blockIdx.x * QR;
#pragma unroll
  for (int r = 0; r < QR; ++r) hT[tid][r] = hin[(i0 + r) * HH + tid];
  __syncthreads();
  float qa0 = 0.f, qa1 = 0.f, ka0 = 0.f, ka1 = 0.f, va0 = 0.f, va1 = 0.f;
#pragma unroll 4
  for (int d = 0; d < HH; ++d) {
    float wq = WqT[d * HH + tid];
    float wk = WkT[d * HH + tid];
    float wv = WvT[d * HH + tid];
    float2 hh = *(const float2*)&hT[d][0];
    qa0 = fmaf(hh.x, wq, qa0); qa1 = fmaf(hh.y, wq, qa1);
    ka0 = fmaf(hh.x, wk, ka0); ka1 = fmaf(hh.y, wk, ka1);
    va0 = fmaf(hh.x, wv, va0); va1 = fmaf(hh.y, wv, va1);
  }
  const float scale = 0.08838834764831845f;  // 1/sqrt(128), folded into q
  float bqv = bq[tid], bkv = bk[tid], bvv = bv[tid];
  q[(i0 + 0) * HH + tid] = (qa0 + bqv) * scale;
  q[(i0 + 1) * HH + tid] = (qa1 + bqv) * scale;
  v[(i0 + 0) * HH + tid] = va0 + bvv;
  v[(i0 + 1) * HH + tid] = va1 + bvv;
  float2 kk = make_float2(ka0 + bkv, ka1 + bkv);
  *(float2*)&kT[tid * NN + i0] = kk;   // kT[d][j]
}

// ---------------- fused attention + edge-weighted coordinate update (1 row/block) ----------------
__global__ __launch_bounds__(TPB)
void fused_kernel(const float* __restrict__ q, const float* __restrict__ kT,
                  const float* __restrict__ v, const float* __restrict__ hin,
                  const float* __restrict__ x,
                  const float* __restrict__ epack, const float* __restrict__ c0p,
                  float* __restrict__ out_h, float* __restrict__ out_x) {
  __shared__ __align__(16) float sp[NN];        // 4KB unnormalized probs (LDS, not global)
  __shared__ __align__(16) float sredh[8][HH];  // 4KB PV partials
  __shared__ float sredm[8];
  __shared__ float sreds[8];
  __shared__ float sredx[8];
  __shared__ float sredy[8];

  const int tid = threadIdx.x;
  const int lane = tid & 63;
  const int wid = tid >> 6;
  const int i = blockIdx.x;

  // ---- scores: thread owns j0=2*tid, j1=2*tid+1 (q via SGPR broadcast, pre-scaled)
  float s0 = 0.f, s1 = 0.f;
  const float2* kT2 = (const float2*)kT;
#pragma unroll 8
  for (int d = 0; d < HH; ++d) {
    float2 kk = kT2[d * (NN / 2) + tid];   // coalesced
    float qd = q[i * HH + d];              // wave-uniform -> s_load
    s0 = fmaf(qd, kk.x, s0);
    s1 = fmaf(qd, kk.y, s1);
  }

  // ---- row max (64-lane butterfly, then 8 wave partials)
  float mv = wmaxf(fmaxf(s0, s1));
  if (lane == 0) sredm[wid] = mv;
  __syncthreads();
  float mm = sredm[0];
#pragma unroll
  for (int w2 = 1; w2 < 8; ++w2) mm = fmaxf(mm, sredm[w2]);

  // ---- exp (unnormalized p) -> LDS, row sum
  float e0 = __expf(s0 - mm), e1 = __expf(s1 - mm);
  *(float2*)&sp[2 * tid] = make_float2(e0, e1);
  float sv = wsumf(e0 + e1);
  if (lane == 0) sreds[wid] = sv;
  __syncthreads();   // also makes sp visible
  float ss = sreds[0];
#pragma unroll
  for (int w2 = 1; w2 < 8; ++w2) ss += sreds[w2];
  const float inv = 1.f / ss;

  // ---- agg_h = p @ v   (8 j-splits x 64 lanes, 2 features per lane, coalesced v)
  const int o2 = (tid & 63) * 2;
  const int spn = tid >> 6;   // 0..7 (wave-uniform)
  float h0 = 0.f, h1 = 0.f;
#pragma unroll 4
  for (int jj = 0; jj < NN / 8; ++jj) {
    int j = spn * (NN / 8) + jj;
    float2 vv = *(const float2*)&v[j * HH + o2];  // coalesced
    float pp = sp[j];                             // uniform LDS broadcast
    h0 = fmaf(pp, vv.x, h0);
    h1 = fmaf(pp, vv.y, h1);
  }
  *(float2*)&sredh[spn][o2] = make_float2(h0, h1);

  // ---- edge-weighted coordinate update (pure VALU; overlaps PV reduce)
  float4 xx = *(const float4*)&x[4 * tid];   // {xj0.x, xj0.y, xj1.x, xj1.y}
  float xix = x[i * 2 + 0], xiy = x[i * 2 + 1];   // uniform
  float dxa = xix - xx.x, dya = xiy - xx.y;
  float dxb = xix - xx.z, dyb = xiy - xx.w;
  float wa = 0.f, wb = 0.f;
  const float4* ep4 = (const float4*)epack;
#pragma unroll 4
  for (int t = 0; t < HH; ++t) {
    float4 e = ep4[t];   // wave-uniform {We1_0, We1_1, be1, u}
    float aa = fmaxf(fmaf(e.x, dxa, fmaf(e.y, dya, e.z)), 0.f);
    wa = fmaf(e.w, aa, wa);
    float bb = fmaxf(fmaf(e.x, dxb, fmaf(e.y, dyb, e.z)), 0.f);
    wb = fmaf(e.w, bb, wb);
  }
  const float c0 = c0p[0];
  float cwa = e0 * (wa + c0);
  float cwb = e1 * (wb + c0);
  float rx = fmaf(cwa, dxa, cwb * dxb);
  float ry = fmaf(cwa, dya, cwb * dyb);
  rx = wsumf(rx);
  ry = wsumf(ry);
  if (lane == 0) { sredx[wid] = rx; sredy[wid] = ry; }

  __syncthreads();   // sredh + sredx/y ready

  if (tid < HH) {
    float hv = 0.f;
#pragma unroll
    for (int s2 = 0; s2 < 8; ++s2) hv += sredh[s2][tid];
    out_h[i * HH + tid] = hin[i * HH + tid] + hv * inv;
  }
  if (tid == 0) {
    float sx = 0.f, sy = 0.f;
#pragma unroll
    for (int w2 = 0; w2 < 8; ++w2) { sx += sredx[w2]; sy += sredy[w2]; }
    out_x[i * 2 + 0] = x[i * 2 + 0] + sx * inv;
    out_x[i * 2 + 1] = x[i * 2 + 1] + sy * inv;
  }
}

extern "C" void kernel_launch(void* const* d_in, const int* in_sizes, int n_in,
                              void* d_out, int out_size, void* d_ws, size_t ws_size,
                              hipStream_t stream) {
  (void)in_sizes; (void)n_in; (void)out_size; (void)ws_size;
  const float* h   = (const float*)d_in[0];
  const float* x   = (const float*)d_in[1];
  // d_in[2] = batch (all zeros, unused)
  const float* Wq  = (const float*)d_in[3];
  const float* bq  = (const float*)d_in[4];
  const float* Wk  = (const float*)d_in[5];
  const float* bk  = (const float*)d_in[6];
  const float* Wv  = (const float*)d_in[7];
  const float* bv  = (const float*)d_in[8];
  const float* We1 = (const float*)d_in[9];
  const float* be1 = (const float*)d_in[10];
  const float* We2 = (const float*)d_in[11];
  const float* be2 = (const float*)d_in[12];
  const float* Wc  = (const float*)d_in[13];
  const float* bc  = (const float*)d_in[14];

  float* ws  = (float*)d_ws;
  float* q_  = ws;                  // N*H (pre-scaled by 1/sqrt(H))
  float* kT  = q_ + NN * HH;        // N*H  (transposed: [d][j])
  float* v_  = kT + NN * HH;        // N*H
  float* WqT = v_ + NN * HH;        // H*H
  float* WkT = WqT + HH * HH;
  float* WvT = WkT + HH * HH;
  float* ep  = WvT + HH * HH;       // 4*H packed edge params
  float* c0  = ep + 4 * HH;         // 1 (+pad)

  float* out_h = (float*)d_out;            // N*H
  float* out_x = out_h + NN * HH;          // N*2

  prep_kernel<<<dim3(HH), dim3(128), 0, stream>>>(
      Wq, Wk, Wv, We1, be1, We2, be2, Wc, bc, WqT, WkT, WvT, ep, c0);
  qkv_kernel<<<dim3(NN / QR), dim3(128), 0, stream>>>(
      h, WqT, WkT, WvT, bq, bk, bv, q_, kT, v_);
  fused_kernel<<<dim3(NN), dim3(TPB), 0, stream>>>(
      q_, kT, v_, h, x, ep, c0, out_h, out_x);
}

// Round 3
// 157.595 us; speedup vs baseline: 1.0413x; 1.0413x over previous
//
#include <hip/hip_runtime.h>

#define NN 1024
#define HH 128
#define QR 2
#define TPB 1024
#define RPB 4

__device__ __forceinline__ float4 wmax4(float4 v) {
#pragma unroll
  for (int off = 1; off < 64; off <<= 1) {
    v.x = fmaxf(v.x, __shfl_xor(v.x, off));
    v.y = fmaxf(v.y, __shfl_xor(v.y, off));
    v.z = fmaxf(v.z, __shfl_xor(v.z, off));
    v.w = fmaxf(v.w, __shfl_xor(v.w, off));
  }
  return v;
}
__device__ __forceinline__ float4 wsum4(float4 v) {
#pragma unroll
  for (int off = 1; off < 64; off <<= 1) {
    v.x += __shfl_xor(v.x, off);
    v.y += __shfl_xor(v.y, off);
    v.z += __shfl_xor(v.z, off);
    v.w += __shfl_xor(v.w, off);
  }
  return v;
}

// ---------------- prep: W transposes + edge param pack + c0 ----------------
__global__ __launch_bounds__(128)
void prep_kernel(const float* __restrict__ Wq, const float* __restrict__ Wk,
                 const float* __restrict__ Wv, const float* __restrict__ We1,
                 const float* __restrict__ be1, const float* __restrict__ We2,
                 const float* __restrict__ be2, const float* __restrict__ Wc,
                 const float* __restrict__ bc,
                 float* __restrict__ WqT, float* __restrict__ WkT,
                 float* __restrict__ WvT, float* __restrict__ epack,
                 float* __restrict__ c0) {
  const int d = blockIdx.x;
  const int o = threadIdx.x;
  WqT[d * HH + o] = Wq[o * HH + d];
  WkT[d * HH + o] = Wk[o * HH + d];
  WvT[d * HH + o] = Wv[o * HH + d];
  if (d == 0) {
    // u[t] = sum_e Wc[e] * We2[e][t]   (fold Wc @ We2)
    float uu = 0.f;
    for (int e = 0; e < HH; ++e) uu = fmaf(Wc[e], We2[e * HH + o], uu);
    epack[o * 4 + 0] = We1[2 * o];
    epack[o * 4 + 1] = We1[2 * o + 1];
    epack[o * 4 + 2] = be1[o];
    epack[o * 4 + 3] = uu;
    if (o == 0) {
      float s = bc[0];
      for (int e = 0; e < HH; ++e) s = fmaf(Wc[e], be2[e], s);
      c0[0] = s;
    }
  }
}

// ---------------- qkv projections: q (pre-scaled), v row-major; k transposed ----------------
__global__ __launch_bounds__(128)
void qkv_kernel(const float* __restrict__ hin,
                const float* __restrict__ WqT, const float* __restrict__ WkT,
                const float* __restrict__ WvT,
                const float* __restrict__ bq, const float* __restrict__ bk,
                const float* __restrict__ bv,
                float* __restrict__ q, float* __restrict__ kT,
                float* __restrict__ v) {
  __shared__ __align__(16) float hT[HH][QR];
  const int tid = threadIdx.x;   // output feature o
  const int i0 = blockIdx.x * QR;
#pragma unroll
  for (int r = 0; r < QR; ++r) hT[tid][r] = hin[(i0 + r) * HH + tid];
  __syncthreads();
  float qa0 = 0.f, qa1 = 0.f, ka0 = 0.f, ka1 = 0.f, va0 = 0.f, va1 = 0.f;
#pragma unroll 4
  for (int d = 0; d < HH; ++d) {
    float wq = WqT[d * HH + tid];
    float wk = WkT[d * HH + tid];
    float wv = WvT[d * HH + tid];
    float2 hh = *(const float2*)&hT[d][0];
    qa0 = fmaf(hh.x, wq, qa0); qa1 = fmaf(hh.y, wq, qa1);
    ka0 = fmaf(hh.x, wk, ka0); ka1 = fmaf(hh.y, wk, ka1);
    va0 = fmaf(hh.x, wv, va0); va1 = fmaf(hh.y, wv, va1);
  }
  const float scale = 0.08838834764831845f;  // 1/sqrt(128), folded into q
  float bqv = bq[tid], bkv = bk[tid], bvv = bv[tid];
  q[(i0 + 0) * HH + tid] = (qa0 + bqv) * scale;
  q[(i0 + 1) * HH + tid] = (qa1 + bqv) * scale;
  v[(i0 + 0) * HH + tid] = va0 + bvv;
  v[(i0 + 1) * HH + tid] = va1 + bvv;
  float2 kk = make_float2(ka0 + bkv, ka1 + bkv);
  *(float2*)&kT[tid * NN + i0] = kk;   // kT[d][j]
}

// ---------------- fused attention + edge-weighted coordinate update ----------------
// grid 256, 1024 threads, 4 rows/block, 1 column j per thread.
__global__ __launch_bounds__(TPB)
void fused_kernel(const float* __restrict__ q, const float* __restrict__ kT,
                  const float* __restrict__ v, const float* __restrict__ hin,
                  const float* __restrict__ x,
                  const float* __restrict__ epack, const float* __restrict__ c0p,
                  float* __restrict__ out_h, float* __restrict__ out_x) {
  __shared__ __align__(16) float4 sp4[NN];         // 16KB {e0,e1,e2,e3} per j
  __shared__ __align__(16) float4 sredh4[8][HH];   // 16KB PV partials
  __shared__ __align__(16) float4 stab[HH];        // 2KB  s_i[t] per row
  __shared__ __align__(16) float4 sredm[16];
  __shared__ __align__(16) float4 sreds[16];
  __shared__ __align__(16) float4 sredx[16];
  __shared__ __align__(16) float4 sredy[16];

  const int tid = threadIdx.x;
  const int lane = tid & 63;
  const int wid = tid >> 6;       // 0..15
  const int i0 = blockIdx.x * RPB;
  const int j = tid;
  const float4* ep4 = (const float4*)epack;

  // ---- phase 0: s_i table: stab[t][r] = We1[t]·x[i0+r] + be1[t]
  if (tid < 4 * HH) {
    const int t = tid >> 2, r = tid & 3;
    float4 e = ep4[t];
    float xr0 = x[(i0 + r) * 2 + 0], xr1 = x[(i0 + r) * 2 + 1];
    ((float*)&stab[t])[r] = fmaf(e.x, xr0, fmaf(e.y, xr1, e.z));
  }

  // ---- scores: thread owns column j; 4 rows via SGPR-broadcast q
  const float* qb = q + i0 * HH;
  float s0 = 0.f, s1 = 0.f, s2 = 0.f, s3 = 0.f;
#pragma unroll 8
  for (int d = 0; d < HH; ++d) {
    float kk = kT[d * NN + j];          // coalesced dword
    float q0 = qb[0 * HH + d];          // wave-uniform -> s_load
    float q1 = qb[1 * HH + d];
    float q2 = qb[2 * HH + d];
    float q3 = qb[3 * HH + d];
    s0 = fmaf(q0, kk, s0);
    s1 = fmaf(q1, kk, s1);
    s2 = fmaf(q2, kk, s2);
    s3 = fmaf(q3, kk, s3);
  }

  // ---- row max
  float4 mv = wmax4(make_float4(s0, s1, s2, s3));
  if (lane == 0) sredm[wid] = mv;
  __syncthreads();   // also publishes stab
  float4 mm = sredm[0];
#pragma unroll
  for (int w2 = 1; w2 < 16; ++w2) {
    float4 t4 = sredm[w2];
    mm.x = fmaxf(mm.x, t4.x); mm.y = fmaxf(mm.y, t4.y);
    mm.z = fmaxf(mm.z, t4.z); mm.w = fmaxf(mm.w, t4.w);
  }

  // ---- exp -> LDS, row sums
  float e0 = __expf(s0 - mm.x), e1 = __expf(s1 - mm.y);
  float e2 = __expf(s2 - mm.z), e3 = __expf(s3 - mm.w);
  sp4[j] = make_float4(e0, e1, e2, e3);
  float4 sv = wsum4(make_float4(e0, e1, e2, e3));
  if (lane == 0) sreds[wid] = sv;
  __syncthreads();   // publishes sp4 + sreds
  float4 ssv = sreds[0];
#pragma unroll
  for (int w2 = 1; w2 < 16; ++w2) {
    float4 t4 = sreds[w2];
    ssv.x += t4.x; ssv.y += t4.y; ssv.z += t4.z; ssv.w += t4.w;
  }
  const float4 inv4 = make_float4(1.f / ssv.x, 1.f / ssv.y, 1.f / ssv.z, 1.f / ssv.w);

  // ---- edge loop: w_j = a·xj, arg_r = s_i[t][r] - w_j  (separable form)
  float2 xj = *(const float2*)&x[2 * j];
  float wa0 = 0.f, wa1 = 0.f, wa2 = 0.f, wa3 = 0.f;
#pragma unroll 4
  for (int t = 0; t < HH; ++t) {
    float4 e = ep4[t];      // uniform {a, b, be1, u}
    float4 st = stab[t];    // uniform LDS broadcast
    float w = fmaf(e.x, xj.x, e.y * xj.y);
    wa0 = fmaf(e.w, fmaxf(st.x - w, 0.f), wa0);
    wa1 = fmaf(e.w, fmaxf(st.y - w, 0.f), wa1);
    wa2 = fmaf(e.w, fmaxf(st.z - w, 0.f), wa2);
    wa3 = fmaf(e.w, fmaxf(st.w - w, 0.f), wa3);
  }
  const float c0 = c0p[0];
  float cw0 = e0 * (wa0 + c0), cw1 = e1 * (wa1 + c0);
  float cw2 = e2 * (wa2 + c0), cw3 = e3 * (wa3 + c0);
  float xi0x = x[(i0 + 0) * 2 + 0], xi0y = x[(i0 + 0) * 2 + 1];
  float xi1x = x[(i0 + 1) * 2 + 0], xi1y = x[(i0 + 1) * 2 + 1];
  float xi2x = x[(i0 + 2) * 2 + 0], xi2y = x[(i0 + 2) * 2 + 1];
  float xi3x = x[(i0 + 3) * 2 + 0], xi3y = x[(i0 + 3) * 2 + 1];
  float4 rx = wsum4(make_float4(cw0 * (xi0x - xj.x), cw1 * (xi1x - xj.x),
                                cw2 * (xi2x - xj.x), cw3 * (xi3x - xj.x)));
  float4 ry = wsum4(make_float4(cw0 * (xi0y - xj.y), cw1 * (xi1y - xj.y),
                                cw2 * (xi2y - xj.y), cw3 * (xi3y - xj.y)));
  if (lane == 0) { sredx[wid] = rx; sredy[wid] = ry; }

  // ---- agg_h = p @ v: thread = (feature o, j-chunk c), 8 chunks x 128 j
  const int o = tid & 127;
  const int c = tid >> 7;   // 0..7 (wave-uniform)
  float h0 = 0.f, h1 = 0.f, h2 = 0.f, h3 = 0.f;
#pragma unroll 4
  for (int jj = 0; jj < NN / 8; ++jj) {
    int jv = c * (NN / 8) + jj;
    float vv = v[jv * HH + o];   // coalesced dword
    float4 pp = sp4[jv];         // uniform LDS broadcast
    h0 = fmaf(pp.x, vv, h0);
    h1 = fmaf(pp.y, vv, h1);
    h2 = fmaf(pp.z, vv, h2);
    h3 = fmaf(pp.w, vv, h3);
  }
  sredh4[c][o] = make_float4(h0, h1, h2, h3);
  __syncthreads();   // publishes sredh4 + sredx/y

  // ---- epilogue
  if (tid < 4 * HH) {
    const int r = tid >> 7, oo = tid & 127;
    float hv = 0.f;
#pragma unroll
    for (int c2 = 0; c2 < 8; ++c2) hv += ((const float*)&sredh4[c2][oo])[r];
    const int row = i0 + r;
    out_h[row * HH + oo] = hin[row * HH + oo] + hv * ((const float*)&inv4)[r];
  }
  if (tid < 4) {
    const int r = tid;
    float sx = 0.f, sy = 0.f;
#pragma unroll
    for (int w2 = 0; w2 < 16; ++w2) {
      sx += ((const float*)&sredx[w2])[r];
      sy += ((const float*)&sredy[w2])[r];
    }
    const int row = i0 + r;
    float invr = ((const float*)&inv4)[r];
    out_x[row * 2 + 0] = x[row * 2 + 0] + sx * invr;
    out_x[row * 2 + 1] = x[row * 2 + 1] + sy * invr;
  }
}

extern "C" void kernel_launch(void* const* d_in, const int* in_sizes, int n_in,
                              void* d_out, int out_size, void* d_ws, size_t ws_size,
                              hipStream_t stream) {
  (void)in_sizes; (void)n_in; (void)out_size; (void)ws_size;
  const float* h   = (const float*)d_in[0];
  const float* x   = (const float*)d_in[1];
  // d_in[2] = batch (all zeros, unused)
  const float* Wq  = (const float*)d_in[3];
  const float* bq  = (const float*)d_in[4];
  const float* Wk  = (const float*)d_in[5];
  const float* bk  = (const float*)d_in[6];
  const float* Wv  = (const float*)d_in[7];
  const float* bv  = (const float*)d_in[8];
  const float* We1 = (const float*)d_in[9];
  const float* be1 = (const float*)d_in[10];
  const float* We2 = (const float*)d_in[11];
  const float* be2 = (const float*)d_in[12];
  const float* Wc  = (const float*)d_in[13];
  const float* bc  = (const float*)d_in[14];

  float* ws  = (float*)d_ws;
  float* q_  = ws;                  // N*H (pre-scaled by 1/sqrt(H))
  float* kT  = q_ + NN * HH;        // N*H  (transposed: [d][j])
  float* v_  = kT + NN * HH;        // N*H
  float* WqT = v_ + NN * HH;        // H*H
  float* WkT = WqT + HH * HH;
  float* WvT = WkT + HH * HH;
  float* ep  = WvT + HH * HH;       // 4*H packed edge params
  float* c0  = ep + 4 * HH;         // 1 (+pad)

  float* out_h = (float*)d_out;            // N*H
  float* out_x = out_h + NN * HH;          // N*2

  prep_kernel<<<dim3(HH), dim3(128), 0, stream>>>(
      Wq, Wk, Wv, We1, be1, We2, be2, Wc, bc, WqT, WkT, WvT, ep, c0);
  qkv_kernel<<<dim3(NN / QR), dim3(128), 0, stream>>>(
      h, WqT, WkT, WvT, bq, bk, bv, q_, kT, v_);
  fused_kernel<<<dim3(NN / RPB), dim3(TPB), 0, stream>>>(
      q_, kT, v_, h, x, ep, c0, out_h, out_x);
}

// Round 6
// 135.942 us; speedup vs baseline: 1.2072x; 1.1593x over previous
//
#include <hip/hip_runtime.h>
#include <hip/hip_fp16.h>

#define NN 1024
#define HH 128
#define QR 2
#define TPB 1024

typedef _Float16 f16x2_t __attribute__((ext_vector_type(2)));

__device__ __forceinline__ float dot2(__half2 a, __half2 b, float c) {
#if __has_builtin(__builtin_amdgcn_fdot2)
  return __builtin_amdgcn_fdot2(__builtin_bit_cast(f16x2_t, a),
                                __builtin_bit_cast(f16x2_t, b), c, false);
#else
  return fmaf(__low2float(a), __low2float(b),
              fmaf(__high2float(a), __high2float(b), c));
#endif
}

// packed-f16 relu: max(a, 0) per half (v_pk_max_f16); ROCm lacks __hmax2
__device__ __forceinline__ __half2 relu2(__half2 a) {
#if __has_builtin(__builtin_elementwise_max)
  f16x2_t v = __builtin_bit_cast(f16x2_t, a);
  f16x2_t z = {(_Float16)0.f, (_Float16)0.f};
  return __builtin_bit_cast(__half2, __builtin_elementwise_max(v, z));
#else
  unsigned int av = __builtin_bit_cast(unsigned int, a);
  unsigned int rv;
  asm("v_pk_max_f16 %0, %1, 0" : "=v"(rv) : "v"(av));
  return __builtin_bit_cast(__half2, rv);
#endif
}

__device__ __forceinline__ float2 wmax2(float2 v) {
#pragma unroll
  for (int off = 1; off < 64; off <<= 1) {
    v.x = fmaxf(v.x, __shfl_xor(v.x, off));
    v.y = fmaxf(v.y, __shfl_xor(v.y, off));
  }
  return v;
}
__device__ __forceinline__ float2 wsum2(float2 v) {
#pragma unroll
  for (int off = 1; off < 64; off <<= 1) {
    v.x += __shfl_xor(v.x, off);
    v.y += __shfl_xor(v.y, off);
  }
  return v;
}

// ---------------- prep: W transposes + edge params (f32 + packed f16) + c0 ----------------
__global__ __launch_bounds__(128)
void prep_kernel(const float* __restrict__ Wq, const float* __restrict__ Wk,
                 const float* __restrict__ Wv, const float* __restrict__ We1,
                 const float* __restrict__ be1, const float* __restrict__ We2,
                 const float* __restrict__ be2, const float* __restrict__ Wc,
                 const float* __restrict__ bc,
                 float* __restrict__ WqT, float* __restrict__ WkT,
                 float* __restrict__ WvT, float* __restrict__ epack,
                 float* __restrict__ c0,
                 __half2* __restrict__ aB, __half2* __restrict__ bB,
                 __half2* __restrict__ uB) {
  __shared__ float su[HH];
  const int d = blockIdx.x;
  const int o = threadIdx.x;
  WqT[d * HH + o] = Wq[o * HH + d];
  WkT[d * HH + o] = Wk[o * HH + d];
  WvT[d * HH + o] = Wv[o * HH + d];
  if (d == 0) {
    // u[t] = sum_e Wc[e] * We2[e][t]   (fold Wc @ We2)
    float uu = 0.f;
    for (int e = 0; e < HH; ++e) uu = fmaf(Wc[e], We2[e * HH + o], uu);
    su[o] = uu;
    epack[o * 4 + 0] = We1[2 * o];
    epack[o * 4 + 1] = We1[2 * o + 1];
    epack[o * 4 + 2] = be1[o];
    epack[o * 4 + 3] = uu;
    if (o == 0) {
      float s = bc[0];
      for (int e = 0; e < HH; ++e) s = fmaf(Wc[e], be2[e], s);
      c0[0] = s;
    }
    __syncthreads();
    if (o < 64) {  // packed f16 over t-pairs (t = 2o, 2o+1)
      aB[o] = __halves2half2(__float2half(We1[4 * o]), __float2half(We1[4 * o + 2]));
      bB[o] = __halves2half2(__float2half(We1[4 * o + 1]), __float2half(We1[4 * o + 3]));
      uB[o] = __halves2half2(__float2half(su[2 * o]), __float2half(su[2 * o + 1]));
    }
  }
}

// ---------------- qkv: f16 outputs; q scaled; k packed over d-pairs [dp][j][2] ----------------
__global__ __launch_bounds__(128)
void qkv_kernel(const float* __restrict__ hin,
                const float* __restrict__ WqT, const float* __restrict__ WkT,
                const float* __restrict__ WvT,
                const float* __restrict__ bq, const float* __restrict__ bk,
                const float* __restrict__ bv,
                __half* __restrict__ q16, __half* __restrict__ kP,
                __half* __restrict__ v16) {
  __shared__ __align__(16) float hT[HH][QR];
  const int tid = threadIdx.x;   // output feature o (= d for k-pack)
  const int i0 = blockIdx.x * QR;
#pragma unroll
  for (int r = 0; r < QR; ++r) hT[tid][r] = hin[(i0 + r) * HH + tid];
  __syncthreads();
  float qa0 = 0.f, qa1 = 0.f, ka0 = 0.f, ka1 = 0.f, va0 = 0.f, va1 = 0.f;
#pragma unroll 4
  for (int d = 0; d < HH; ++d) {
    float wq = WqT[d * HH + tid];
    float wk = WkT[d * HH + tid];
    float wv = WvT[d * HH + tid];
    float2 hh = *(const float2*)&hT[d][0];
    qa0 = fmaf(hh.x, wq, qa0); qa1 = fmaf(hh.y, wq, qa1);
    ka0 = fmaf(hh.x, wk, ka0); ka1 = fmaf(hh.y, wk, ka1);
    va0 = fmaf(hh.x, wv, va0); va1 = fmaf(hh.y, wv, va1);
  }
  const float scale = 0.08838834764831845f;  // 1/sqrt(128), folded into q
  float bqv = bq[tid], bkv = bk[tid], bvv = bv[tid];
  q16[(i0 + 0) * HH + tid] = __float2half((qa0 + bqv) * scale);
  q16[(i0 + 1) * HH + tid] = __float2half((qa1 + bqv) * scale);
  v16[(i0 + 0) * HH + tid] = __float2half(va0 + bvv);
  v16[(i0 + 1) * HH + tid] = __float2half(va1 + bvv);
  // k: pack feature pair (2dp, 2dp+1) for columns j = i0, i0+1
  float kb0 = ka0 + bkv, kb1 = ka1 + bkv;
  float pr0 = __shfl_xor(kb0, 1);
  float pr1 = __shfl_xor(kb1, 1);
  if ((tid & 1) == 0) {
    const int dp = tid >> 1;
    __half2 w0 = __halves2half2(__float2half(kb0), __float2half(pr0));
    __half2 w1 = __halves2half2(__float2half(kb1), __float2half(pr1));
    *(__half2*)&kP[dp * (2 * NN) + 2 * i0]     = w0;  // j = i0
    *(__half2*)&kP[dp * (2 * NN) + 2 * i0 + 2] = w1;  // j = i0+1
  }
}

// ---------------- fused attention + edge-weighted coordinate update ----------------
// grid 512, 1024 threads, 2 rows/block, 1 column j per thread. 2 blocks/CU.
__global__ __launch_bounds__(TPB, 8)
void fused_kernel(const __half* __restrict__ q16, const __half* __restrict__ kP,
                  const __half* __restrict__ v16, const float* __restrict__ hin,
                  const float* __restrict__ x, const float* __restrict__ epack,
                  const __half2* __restrict__ aB, const __half2* __restrict__ bB,
                  const __half2* __restrict__ uB, const float* __restrict__ c0p,
                  float* __restrict__ out_h, float* __restrict__ out_x) {
  __shared__ __align__(16) float spA[NN];          // 4KB p row 0
  __shared__ __align__(16) float spB[NN];          // 4KB p row 1
  __shared__ __align__(16) float4 sredh[16][64];   // 16KB PV partials
  __shared__ __half2 stabA[64];                    // s_i0[t] packed over t-pairs
  __shared__ __half2 stabB[64];                    // s_i1[t]
  __shared__ float2 sredm[16], sreds[16], sredx[16], sredy[16];

  const int tid = threadIdx.x;
  const int lane = tid & 63;
  const int wid = tid >> 6;       // 0..15
  const int i0 = blockIdx.x * 2;
  const int j = tid;

  // ---- phase 0: stab[t][r] = We1[t]·x[i0+r] + be1[t], packed over t-pairs
  if (tid < 64) {
    const float4 ea = ((const float4*)epack)[2 * tid];
    const float4 eb = ((const float4*)epack)[2 * tid + 1];
    float x0x = x[i0 * 2 + 0], x0y = x[i0 * 2 + 1];
    float x1x = x[i0 * 2 + 2], x1y = x[i0 * 2 + 3];
    stabA[tid] = __halves2half2(
        __float2half(fmaf(ea.x, x0x, fmaf(ea.y, x0y, ea.z))),
        __float2half(fmaf(eb.x, x0x, fmaf(eb.y, x0y, eb.z))));
    stabB[tid] = __halves2half2(
        __float2half(fmaf(ea.x, x1x, fmaf(ea.y, x1y, ea.z))),
        __float2half(fmaf(eb.x, x1x, fmaf(eb.y, x1y, eb.z))));
  }

  // ---- scores via dot2: thread owns column j, 2 rows
  const __half2* q0p = (const __half2*)(q16 + (i0 + 0) * HH);
  const __half2* q1p = (const __half2*)(q16 + (i0 + 1) * HH);
  float s0 = 0.f, s1 = 0.f;
#pragma unroll 8
  for (int dp = 0; dp < HH / 2; ++dp) {
    __half2 kk = *(const __half2*)&kP[dp * (2 * NN) + 2 * j];  // coalesced dword
    s0 = dot2(kk, q0p[dp], s0);   // q uniform -> s_load
    s1 = dot2(kk, q1p[dp], s1);
  }

  // ---- row max
  float2 mv = wmax2(make_float2(s0, s1));
  if (lane == 0) sredm[wid] = mv;
  __syncthreads();   // also publishes stab
  float2 mm = sredm[0];
#pragma unroll
  for (int w2 = 1; w2 < 16; ++w2) {
    float2 t2 = sredm[w2];
    mm.x = fmaxf(mm.x, t2.x); mm.y = fmaxf(mm.y, t2.y);
  }

  // ---- exp -> LDS, row sums
  float e0 = __expf(s0 - mm.x), e1 = __expf(s1 - mm.y);
  spA[j] = e0; spB[j] = e1;
  float2 sv = wsum2(make_float2(e0, e1));
  if (lane == 0) sreds[wid] = sv;
  __syncthreads();   // publishes sp + sreds
  float2 ssv = sreds[0];
#pragma unroll
  for (int w2 = 1; w2 < 16; ++w2) { ssv.x += sreds[w2].x; ssv.y += sreds[w2].y; }
  const float inv0 = 1.f / ssv.x, inv1 = 1.f / ssv.y;

  // ---- agg_h = p @ v: thread = (o-pair, j-chunk), 16 chunks x 64 j
  {
    const int op = tid & 63;        // o-pair (lane) -> coalesced v reads
    const int c = tid >> 6;         // chunk (wave-uniform)
    float hA0 = 0.f, hB0 = 0.f, hA1 = 0.f, hB1 = 0.f;
#pragma unroll 4
    for (int jj = 0; jj < NN / 16; ++jj) {
      int jv = c * (NN / 16) + jj;
      __half2 vv = *(const __half2*)&v16[jv * HH + 2 * op];  // coalesced dword
      float vx = __low2float(vv), vy = __high2float(vv);
      float p0 = spA[jv];   // uniform LDS broadcast
      float p1 = spB[jv];
      hA0 = fmaf(p0, vx, hA0); hB0 = fmaf(p0, vy, hB0);
      hA1 = fmaf(p1, vx, hA1); hB1 = fmaf(p1, vy, hB1);
    }
    sredh[c][op] = make_float4(hA0, hB0, hA1, hB1);
  }

  // ---- edge loop, packed f16 over t-pairs, f32 accumulate via dot2
  float2 xj = *(const float2*)&x[2 * j];
  __half2 xjx2 = __float2half2_rn(xj.x);
  __half2 xjy2 = __float2half2_rn(xj.y);
  float wa0 = 0.f, wa1 = 0.f;
#pragma unroll 8
  for (int tp = 0; tp < 64; ++tp) {
    __half2 a2 = aB[tp], b2 = bB[tp], u2 = uB[tp];   // uniform -> s_load
    __half2 w2 = __hfma2(a2, xjx2, __hmul2(b2, xjy2));
    wa0 = dot2(u2, relu2(__hsub2(stabA[tp], w2)), wa0);
    wa1 = dot2(u2, relu2(__hsub2(stabB[tp], w2)), wa1);
  }
  const float c0v = c0p[0];
  float cw0 = e0 * (wa0 + c0v);
  float cw1 = e1 * (wa1 + c0v);
  float xi0x = x[i0 * 2 + 0], xi0y = x[i0 * 2 + 1];
  float xi1x = x[i0 * 2 + 2], xi1y = x[i0 * 2 + 3];
  float2 rx = wsum2(make_float2(cw0 * (xi0x - xj.x), cw1 * (xi1x - xj.x)));
  float2 ry = wsum2(make_float2(cw0 * (xi0y - xj.y), cw1 * (xi1y - xj.y)));
  if (lane == 0) { sredx[wid] = rx; sredy[wid] = ry; }

  __syncthreads();   // publishes sredh + sredx/y

  // ---- epilogue
  if (tid < 2 * HH) {
    const int r = tid >> 7, o = tid & 127;
    float hv = 0.f;
#pragma unroll
    for (int c2 = 0; c2 < 16; ++c2)
      hv += ((const float*)&sredh[c2][o >> 1])[(r << 1) | (o & 1)];
    float invr = r ? inv1 : inv0;
    out_h[(i0 + r) * HH + o] = hin[(i0 + r) * HH + o] + hv * invr;
  }
  if (tid < 2) {
    float sx = 0.f, sy = 0.f;
#pragma unroll
    for (int w2 = 0; w2 < 16; ++w2) {
      sx += tid ? sredx[w2].y : sredx[w2].x;
      sy += tid ? sredy[w2].y : sredy[w2].x;
    }
    float invr = tid ? inv1 : inv0;
    out_x[(i0 + tid) * 2 + 0] = x[(i0 + tid) * 2 + 0] + sx * invr;
    out_x[(i0 + tid) * 2 + 1] = x[(i0 + tid) * 2 + 1] + sy * invr;
  }
}

extern "C" void kernel_launch(void* const* d_in, const int* in_sizes, int n_in,
                              void* d_out, int out_size, void* d_ws, size_t ws_size,
                              hipStream_t stream) {
  (void)in_sizes; (void)n_in; (void)out_size; (void)ws_size;
  const float* h   = (const float*)d_in[0];
  const float* x   = (const float*)d_in[1];
  // d_in[2] = batch (all zeros, unused)
  const float* Wq  = (const float*)d_in[3];
  const float* bq  = (const float*)d_in[4];
  const float* Wk  = (const float*)d_in[5];
  const float* bk  = (const float*)d_in[6];
  const float* Wv  = (const float*)d_in[7];
  const float* bv  = (const float*)d_in[8];
  const float* We1 = (const float*)d_in[9];
  const float* be1 = (const float*)d_in[10];
  const float* We2 = (const float*)d_in[11];
  const float* be2 = (const float*)d_in[12];
  const float* Wc  = (const float*)d_in[13];
  const float* bc  = (const float*)d_in[14];

  float* ws   = (float*)d_ws;
  float* WqT  = ws;                   // 16384
  float* WkT  = WqT + HH * HH;        // 16384
  float* WvT  = WkT + HH * HH;        // 16384
  float* ep   = WvT + HH * HH;        // 512 (f32 {a,b,be1,u} per t)
  float* c0   = ep + 4 * HH;          // 8 (padded)
  __half* q16 = (__half*)(c0 + 8);    // N*H halves (scaled q)
  __half* kP  = q16 + NN * HH;        // N*H halves, [dp][j][2] packed
  __half* v16 = kP + NN * HH;         // N*H halves, row-major
  __half2* aB = (__half2*)(v16 + NN * HH);  // 64
  __half2* bB = aB + 64;                    // 64
  __half2* uB = bB + 64;                    // 64

  float* out_h = (float*)d_out;            // N*H
  float* out_x = out_h + NN * HH;          // N*2

  prep_kernel<<<dim3(HH), dim3(128), 0, stream>>>(
      Wq, Wk, Wv, We1, be1, We2, be2, Wc, bc, WqT, WkT, WvT, ep, c0, aB, bB, uB);
  qkv_kernel<<<dim3(NN / QR), dim3(128), 0, stream>>>(
      h, WqT, WkT, WvT, bq, bk, bv, q16, kP, v16);
  fused_kernel<<<dim3(NN / 2), dim3(TPB), 0, stream>>>(
      q16, kP, v16, h, x, ep, aB, bB, uB, c0, out_h, out_x);
}